// Round 11
// baseline (129.501 us; speedup 1.0000x reference)
//
#include <hip/hip_runtime.h>
#include <hip/hip_bf16.h>

#define NN 20000
#define NE 320000
#define XSTB 256    // xcatb row stride (bf16 elems)
#define CAP 96      // per-node bucket capacity (Poisson(16): P(>=96)~1e-47); 96*4B=384B (16B-aligned)

typedef __attribute__((ext_vector_type(8))) short short8v;
typedef __attribute__((ext_vector_type(4))) float float4v;

struct bh4 { __hip_bfloat16 a, b, c, d; };

// Wt layout (all 3 layers): per layer [128][K] bf16.
// rows 0..63 = (Wtop-Wbot)^T -> Pa; rows 64..127 = Wbot^T -> Pb
#define WT_OFF0 0
#define WT_OFF1 (128 * 64)                 // 8192
#define WT_OFF2 (WT_OFF1 + 128 * 128)      // 24576
#define WT_TOT  (WT_OFF2 + 128 * 192)      // 49152 elems

// ---- KZ: zero cursor (20 blocks) || build Wt all layers (192 blocks) ----
__global__ __launch_bounds__(256) void kz_kernel(const float* __restrict__ W0,
                                                 const float* __restrict__ W1,
                                                 const float* __restrict__ W2,
                                                 __hip_bfloat16* __restrict__ Wt,
                                                 int* __restrict__ cursor) {
    int blk = blockIdx.x, tid = threadIdx.x;
    if (blk < 20) {
        int q = blk * 256 + tid;               // 5120 >= 5000 int4
        if (q < NN / 4) *((int4*)cursor + q) = make_int4(0, 0, 0, 0);
    } else {
        int e = (blk - 20) * 256 + tid;        // 49152 exactly
        const float* W;
        int K, off;
        if (e < WT_OFF1) { W = W0; K = 64;  off = WT_OFF0; }
        else if (e < WT_OFF2) { W = W1; K = 128; off = WT_OFF1; }
        else { W = W2; K = 192; off = WT_OFF2; }
        int el = e - off;
        int j = el / K, k = el - j * K;
        float wv;
        if (j < 64) wv = W[(size_t)k * 64 + j] - W[(size_t)(K + k) * 64 + j];
        else        wv = W[(size_t)(K + k) * 64 + (j - 64)];
        Wt[(size_t)off + (size_t)j * K + k] = __float2bfloat16(wv);
    }
}

// ---- K1: gemm0 || bucket CSR fill || x->bf16 ----
// blocks [0,625): gemm0 (A from fp32 x, B from global Wt0); [625,1875): fill;
// [1875,3125): xconv.
__global__ __launch_bounds__(256, 4) void k1_kernel(
    const float* __restrict__ x, const __hip_bfloat16* __restrict__ Wt,
    const int* __restrict__ esrc, const int* __restrict__ edst,
    __hip_bfloat16* __restrict__ xcatb, int* __restrict__ cursor,
    int* __restrict__ elist, float* __restrict__ Pa,
    __hip_bfloat16* __restrict__ Pbb) {
    int blk = blockIdx.x, tid = threadIdx.x;
    int w = tid >> 6, lane = tid & 63;

    if (blk < 625) {
        int wid = blk * 4 + w;                     // 0..2499
        int panel = wid >> 1, half = wid & 1;
        int m = lane & 15, g = lane >> 4;
        const float* aptr = x + (size_t)(panel * 16 + m) * 64 + g * 8;
        const __hip_bfloat16* bptr = Wt + (size_t)(half * 64 + m) * 64 + g * 8;
        float4v acc[4] = {{0.f,0.f,0.f,0.f},{0.f,0.f,0.f,0.f},
                          {0.f,0.f,0.f,0.f},{0.f,0.f,0.f,0.f}};
#pragma unroll
        for (int k0 = 0; k0 < 64; k0 += 32) {
            float4 a0 = *(const float4*)(aptr + k0);
            float4 a1 = *(const float4*)(aptr + k0 + 4);
            __hip_bfloat16 ah[8] = {
                __float2bfloat16(a0.x), __float2bfloat16(a0.y),
                __float2bfloat16(a0.z), __float2bfloat16(a0.w),
                __float2bfloat16(a1.x), __float2bfloat16(a1.y),
                __float2bfloat16(a1.z), __float2bfloat16(a1.w)};
            short8v a = *(const short8v*)ah;
#pragma unroll
            for (int t = 0; t < 4; ++t) {
                short8v bb = *(const short8v*)(bptr + (size_t)t * 16 * 64 + k0);
                acc[t] = __builtin_amdgcn_mfma_f32_16x16x32_bf16(a, bb, acc[t], 0, 0, 0);
            }
        }
        int r0 = panel * 16;
        if (half == 0) {
#pragma unroll
            for (int t = 0; t < 4; ++t)
#pragma unroll
                for (int r = 0; r < 4; ++r)
                    Pa[(size_t)(r0 + g * 4 + r) * 64 + t * 16 + m] = acc[t][r];
        } else {
#pragma unroll
            for (int t = 0; t < 4; ++t)
#pragma unroll
                for (int r = 0; r < 4; ++r)
                    Pbb[(size_t)(r0 + g * 4 + r) * 64 + t * 16 + m] =
                        __float2bfloat16(acc[t][r]);
        }
    } else if (blk < 1875) {
        int i = (blk - 625) * 256 + tid;           // < NE exactly
        int d = edst[i];
        int pos = atomicAdd(cursor + d, 1);
        if (pos < CAP) elist[(size_t)d * CAP + pos] = esrc[i];
    } else {
        int i = (blk - 1875) * 256 + tid;          // 320000 quads exactly
        int n = i >> 4, c4 = (i & 15) << 2;
        float4 v = *(const float4*)(x + (size_t)n * 64 + c4);
        bh4 o = {__float2bfloat16(v.x), __float2bfloat16(v.y),
                 __float2bfloat16(v.z), __float2bfloat16(v.w)};
        *(bh4*)(xcatb + (size_t)n * XSTB + c4) = o;
    }
}

// ---- fused: agg(layer i) for 16 nodes -> LDS + xcatb, then gemm(layer i+1) K=C ----
// 1250 blocks. Phase A: 4 waves x 4 nodes INTERLEAVED (up to 32 gathers in flight).
// Phase B: waves 0,1 (halves).
template <int C>
__global__ __launch_bounds__(256, 4) void fused_kernel(
    const float* __restrict__ PaIn, const __hip_bfloat16* __restrict__ PbbIn,
    const float* __restrict__ b, const int* __restrict__ cnt,
    const int* __restrict__ elist, __hip_bfloat16* __restrict__ xcatb,
    const __hip_bfloat16* __restrict__ Wt, float* __restrict__ PaOut,
    __hip_bfloat16* __restrict__ PbbOut) {
    __shared__ __hip_bfloat16 newt[16][72];
    int tid = threadIdx.x;
    int w = tid >> 6, lane = tid & 63;
    int panel = blockIdx.x;
    int r0 = panel * 16;

    // ---- phase A: 4 nodes per wave, edge chunks of 8, all nodes in flight ----
    int node0 = r0 + w * 4;
    int cc[4];
    float mx[4], pa[4];
    const int* el[4];
#pragma unroll
    for (int nl = 0; nl < 4; ++nl) {
        int node = node0 + nl;
        int c = cnt[node];
        cc[nl] = c > CAP ? CAP : c;
        el[nl] = elist + (size_t)node * CAP;
        mx[nl] = -INFINITY;
        pa[nl] = PaIn[(size_t)node * 64 + lane] + b[lane];
    }
    int cmax = max(max(cc[0], cc[1]), max(cc[2], cc[3]));
    for (int i = 0; i < cmax; i += 8) {
        // index prefetch: 2 wave-uniform int4 per node (safe: bucket is CAP-padded)
        int4 ea[4], eb[4];
#pragma unroll
        for (int nl = 0; nl < 4; ++nl) {
            ea[nl] = *(const int4*)(el[nl] + i);
            eb[nl] = *(const int4*)(el[nl] + i + 4);
        }
        float v[4][8];
#pragma unroll
        for (int nl = 0; nl < 4; ++nl) {
            int c = cc[nl];
            int idx[8] = {ea[nl].x, ea[nl].y, ea[nl].z, ea[nl].w,
                          eb[nl].x, eb[nl].y, eb[nl].z, eb[nl].w};
#pragma unroll
            for (int j = 0; j < 8; ++j) {
                v[nl][j] = -INFINITY;
                if (i + j < c)
                    v[nl][j] = __bfloat162float(PbbIn[(size_t)idx[j] * 64 + lane]);
            }
        }
#pragma unroll
        for (int nl = 0; nl < 4; ++nl) {
            float m0 = fmaxf(fmaxf(v[nl][0], v[nl][1]), fmaxf(v[nl][2], v[nl][3]));
            float m1 = fmaxf(fmaxf(v[nl][4], v[nl][5]), fmaxf(v[nl][6], v[nl][7]));
            mx[nl] = fmaxf(mx[nl], fmaxf(m0, m1));
        }
    }
#pragma unroll
    for (int nl = 0; nl < 4; ++nl) {
        int local = w * 4 + nl;
        float vv = fmaxf(pa[nl] + mx[nl], 0.f);
        __hip_bfloat16 h = __float2bfloat16(vv);
        newt[local][lane] = h;
        xcatb[(size_t)(node0 + nl) * XSTB + (C - 64) + lane] = h;
    }
    __syncthreads();
    if (w >= 2) return;

    // ---- phase B: MFMA gemm for this panel, half = w ----
    int half = w;
    int m = lane & 15, g = lane >> 4;
    const __hip_bfloat16* aptr = xcatb + (size_t)(r0 + m) * XSTB + g * 8;
    const __hip_bfloat16* bptr = Wt + (size_t)(half * 64 + m) * C + g * 8;
    float4v acc[4] = {{0.f,0.f,0.f,0.f},{0.f,0.f,0.f,0.f},
                      {0.f,0.f,0.f,0.f},{0.f,0.f,0.f,0.f}};
#pragma unroll
    for (int k0 = 0; k0 < C; k0 += 32) {
        short8v a;
        if (k0 < C - 64) a = *(const short8v*)(aptr + k0);
        else             a = *(const short8v*)(&newt[m][k0 - (C - 64) + g * 8]);
#pragma unroll
        for (int t = 0; t < 4; ++t) {
            short8v bb = *(const short8v*)(bptr + (size_t)t * 16 * C + k0);
            acc[t] = __builtin_amdgcn_mfma_f32_16x16x32_bf16(a, bb, acc[t], 0, 0, 0);
        }
    }
    if (half == 0) {
#pragma unroll
        for (int t = 0; t < 4; ++t)
#pragma unroll
            for (int r = 0; r < 4; ++r)
                PaOut[(size_t)(r0 + g * 4 + r) * 64 + t * 16 + m] = acc[t][r];
    } else {
#pragma unroll
        for (int t = 0; t < 4; ++t)
#pragma unroll
            for (int r = 0; r < 4; ++r)
                PbbOut[(size_t)(r0 + g * 4 + r) * 64 + t * 16 + m] =
                    __float2bfloat16(acc[t][r]);
    }
}

// ---- last layer agg + final max (4 nodes/block, 1 per wave, ILP-8) ----
__global__ __launch_bounds__(256, 4) void aggf_kernel(
    const float* __restrict__ Pa, const __hip_bfloat16* __restrict__ Pbb,
    const float* __restrict__ b, const int* __restrict__ cnt,
    const int* __restrict__ elist, const __hip_bfloat16* __restrict__ xcatb,
    float* __restrict__ out) {
    __shared__ float sm[4][64];
    int w = threadIdx.x >> 6, lane = threadIdx.x & 63;
    int node = blockIdx.x * 4 + w;                 // 5000*4 = 20000 exactly
    int c = cnt[node];
    if (c > CAP) c = CAP;
    const int* el = elist + (size_t)node * CAP;
    float pa = Pa[(size_t)node * 64 + lane] + b[lane];
    float mx = -INFINITY;
    for (int i = 0; i < c; i += 8) {
        int4 ea = *(const int4*)(el + i);
        int4 eb = *(const int4*)(el + i + 4);
        int idx[8] = {ea.x, ea.y, ea.z, ea.w, eb.x, eb.y, eb.z, eb.w};
        float v[8];
#pragma unroll
        for (int j = 0; j < 8; ++j) {
            v[j] = -INFINITY;
            if (i + j < c) v[j] = __bfloat162float(Pbb[(size_t)idx[j] * 64 + lane]);
        }
        float m0 = fmaxf(fmaxf(v[0], v[1]), fmaxf(v[2], v[3]));
        float m1 = fmaxf(fmaxf(v[4], v[5]), fmaxf(v[6], v[7]));
        mx = fmaxf(mx, fmaxf(m0, m1));
    }
    float vv = fmaxf(pa + mx, 0.f);
    sm[w][lane] = vv;                              // intra-wave produce/consume
    float m;
    if (lane < 48) {
        bh4 q = *(const bh4*)(xcatb + (size_t)node * XSTB + (lane << 2));
        float f0 = __bfloat162float(q.a), f1 = __bfloat162float(q.b);
        float f2 = __bfloat162float(q.c), f3 = __bfloat162float(q.d);
        m = fmaxf(fmaxf(f0, f1), fmaxf(f2, f3));
    } else {
        const float* p = &sm[w][(lane - 48) << 2];
        m = fmaxf(fmaxf(p[0], p[1]), fmaxf(p[2], p[3]));
    }
    out[(size_t)node * 64 + lane] = m;
}

extern "C" void kernel_launch(void* const* d_in, const int* in_sizes, int n_in,
                              void* d_out, int out_size, void* d_ws, size_t ws_size,
                              hipStream_t stream) {
    const float* x = (const float*)d_in[0];
    const float* W0 = (const float*)d_in[1];
    const float* W1 = (const float*)d_in[3];
    const float* W2 = (const float*)d_in[5];
    const float* b0 = (const float*)d_in[2];
    const float* b1 = (const float*)d_in[4];
    const float* b2 = (const float*)d_in[6];
    const int* eidx = (const int*)d_in[7];
    const int* esrc = eidx;
    const int* edst = eidx + NE;
    float* out = (float*)d_out;

    char* w = (char*)d_ws;
    __hip_bfloat16* xcatb = (__hip_bfloat16*)w;  w += (size_t)NN * XSTB * 2;
    float* PaA = (float*)w;                      w += (size_t)NN * 64 * 4;
    __hip_bfloat16* PbbA = (__hip_bfloat16*)w;   w += (size_t)NN * 64 * 2;
    float* PaB = (float*)w;                      w += (size_t)NN * 64 * 4;
    __hip_bfloat16* PbbB = (__hip_bfloat16*)w;   w += (size_t)NN * 64 * 2;
    __hip_bfloat16* Wt = (__hip_bfloat16*)w;     w += (size_t)WT_TOT * 2;
    int* cursor = (int*)w;                       w += (size_t)NN * 4;
    int* elist = (int*)w;

    kz_kernel<<<20 + 192, 256, 0, stream>>>(W0, W1, W2, Wt, cursor);
    k1_kernel<<<3125, 256, 0, stream>>>(x, Wt, esrc, edst, xcatb, cursor, elist,
                                        PaA, PbbA);
    fused_kernel<128><<<1250, 256, 0, stream>>>(PaA, PbbA, b0, cursor, elist, xcatb,
                                                Wt + WT_OFF1, PaB, PbbB);
    fused_kernel<192><<<1250, 256, 0, stream>>>(PaB, PbbB, b1, cursor, elist, xcatb,
                                                Wt + WT_OFF2, PaA, PbbA);
    aggf_kernel<<<5000, 256, 0, stream>>>(PaA, PbbA, b2, cursor, elist, xcatb, out);
}

// Round 12
// 93.555 us; speedup vs baseline: 1.3842x; 1.3842x over previous
//
#include <hip/hip_runtime.h>
#include <hip/hip_bf16.h>

#define NN 20000
#define NE 320000
#define XSTB 256    // xcatb row stride (bf16 elems)
#define CAP 96      // per-node bucket capacity (Poisson(16): P(>=96)~1e-47)

typedef __attribute__((ext_vector_type(8))) short short8v;
typedef __attribute__((ext_vector_type(4))) float float4v;

struct bh4 { __hip_bfloat16 a, b, c, d; };

// Global Wt layout (layers 1,2; layer 0 built in-LDS by gemm0 blocks):
// per layer [128][K] bf16: rows 0..63 = (Wtop-Wbot)^T -> Pa; rows 64..127 = Wbot^T -> Pb
#define WT_OFF1 0
#define WT_OFF2 (128 * 128)
#define WT_TOT  (128 * 128 + 128 * 192)   // 40960 elems

__device__ __forceinline__ float bucket_max(const int* __restrict__ el, int c, int lane,
                                            const __hip_bfloat16* __restrict__ Pbb) {
    float mx = -INFINITY;
    int i = 0;
    for (; i + 4 <= c; i += 4) {
        int s0 = el[i], s1 = el[i + 1], s2 = el[i + 2], s3 = el[i + 3];
        float v0 = __bfloat162float(Pbb[(size_t)s0 * 64 + lane]);
        float v1 = __bfloat162float(Pbb[(size_t)s1 * 64 + lane]);
        float v2 = __bfloat162float(Pbb[(size_t)s2 * 64 + lane]);
        float v3 = __bfloat162float(Pbb[(size_t)s3 * 64 + lane]);
        mx = fmaxf(mx, fmaxf(fmaxf(v0, v1), fmaxf(v2, v3)));
    }
    for (; i < c; ++i)
        mx = fmaxf(mx, __bfloat162float(Pbb[(size_t)el[i] * 64 + lane]));
    return mx;
}

// ---- KZ: zero cursor (tiny) ----
__global__ __launch_bounds__(256) void kz_kernel(int* __restrict__ cursor) {
    int q = blockIdx.x * 256 + threadIdx.x;        // 5120 >= 5000 int4
    if (q < NN / 4) *((int4*)cursor + q) = make_int4(0, 0, 0, 0);
}

// ---- K1: gemm0 || bucket CSR fill || x->bf16 || Wt(1,2) build ----
// blocks [0,625): gemm0; [625,1875): fill; [1875,3125): xconv; [3125,3285): Wt.
__global__ __launch_bounds__(256, 4) void k1_kernel(
    const float* __restrict__ x, const float* __restrict__ W0,
    const float* __restrict__ W1, const float* __restrict__ W2,
    const int* __restrict__ esrc, const int* __restrict__ edst,
    __hip_bfloat16* __restrict__ xcatb, __hip_bfloat16* __restrict__ Wt,
    int* __restrict__ cursor, int* __restrict__ elist,
    float* __restrict__ Pa, __hip_bfloat16* __restrict__ Pbb) {
    __shared__ __hip_bfloat16 Ws0[128][72];
    int blk = blockIdx.x, tid = threadIdx.x;
    int w = tid >> 6, lane = tid & 63;

    if (blk < 625) {
        // build transformed W0 into LDS (coalesced over W0 rows)
        for (int e = tid; e < 4096; e += 256) {
            int r = e >> 6, j = e & 63;            // r = k index, j = out col
            float wt = W0[r * 64 + j];
            float wb = W0[(64 + r) * 64 + j];
            Ws0[j][r] = __float2bfloat16(wt - wb);
            Ws0[64 + j][r] = __float2bfloat16(wb);
        }
        __syncthreads();
        int wid = blk * 4 + w;                     // 0..2499
        int panel = wid >> 1, half = wid & 1;
        int m = lane & 15, g = lane >> 4;
        const float* aptr = x + (size_t)(panel * 16 + m) * 64 + g * 8;
        float4v acc[4] = {{0.f,0.f,0.f,0.f},{0.f,0.f,0.f,0.f},
                          {0.f,0.f,0.f,0.f},{0.f,0.f,0.f,0.f}};
#pragma unroll
        for (int k0 = 0; k0 < 64; k0 += 32) {
            float4 a0 = *(const float4*)(aptr + k0);
            float4 a1 = *(const float4*)(aptr + k0 + 4);
            __hip_bfloat16 ah[8] = {
                __float2bfloat16(a0.x), __float2bfloat16(a0.y),
                __float2bfloat16(a0.z), __float2bfloat16(a0.w),
                __float2bfloat16(a1.x), __float2bfloat16(a1.y),
                __float2bfloat16(a1.z), __float2bfloat16(a1.w)};
            short8v a = *(const short8v*)ah;
#pragma unroll
            for (int t = 0; t < 4; ++t) {
                short8v bb = *(const short8v*)(&Ws0[half * 64 + t * 16 + m][k0 + g * 8]);
                acc[t] = __builtin_amdgcn_mfma_f32_16x16x32_bf16(a, bb, acc[t], 0, 0, 0);
            }
        }
        int r0 = panel * 16;
        if (half == 0) {
#pragma unroll
            for (int t = 0; t < 4; ++t)
#pragma unroll
                for (int r = 0; r < 4; ++r)
                    Pa[(size_t)(r0 + g * 4 + r) * 64 + t * 16 + m] = acc[t][r];
        } else {
#pragma unroll
            for (int t = 0; t < 4; ++t)
#pragma unroll
                for (int r = 0; r < 4; ++r)
                    Pbb[(size_t)(r0 + g * 4 + r) * 64 + t * 16 + m] =
                        __float2bfloat16(acc[t][r]);
        }
    } else if (blk < 1875) {
        int i = (blk - 625) * 256 + tid;           // < NE exactly
        int d = edst[i];
        int pos = atomicAdd(cursor + d, 1);
        if (pos < CAP) elist[(size_t)d * CAP + pos] = esrc[i];
    } else if (blk < 3125) {
        int i = (blk - 1875) * 256 + tid;          // 320000 quads exactly
        int n = i >> 4, c4 = (i & 15) << 2;
        float4 v = *(const float4*)(x + (size_t)n * 64 + c4);
        bh4 o = {__float2bfloat16(v.x), __float2bfloat16(v.y),
                 __float2bfloat16(v.z), __float2bfloat16(v.w)};
        *(bh4*)(xcatb + (size_t)n * XSTB + c4) = o;
    } else {
        int e = (blk - 3125) * 256 + tid;          // 40960 exactly
        const float* W;
        int K, off;
        if (e < WT_OFF2) { W = W1; K = 128; off = WT_OFF1; }
        else             { W = W2; K = 192; off = WT_OFF2; }
        int el = e - off;
        int j = el / K, k = el - j * K;
        float wv;
        if (j < 64) wv = W[(size_t)k * 64 + j] - W[(size_t)(K + k) * 64 + j];
        else        wv = W[(size_t)(K + k) * 64 + (j - 64)];
        Wt[(size_t)off + (size_t)j * K + k] = __float2bfloat16(wv);
    }
}

// ---- fused: agg(layer i) for 16 nodes -> LDS + xcatb, then gemm(layer i+1) K=C ----
// 1250 blocks x 512 threads. Phase A: 8 waves x 2 nodes (halved chain, full
// occupancy during gather). Phase B: waves 0,1 (halves), as before.
template <int C>
__global__ __launch_bounds__(512, 2) void fused_kernel(
    const float* __restrict__ PaIn, const __hip_bfloat16* __restrict__ PbbIn,
    const float* __restrict__ b, const int* __restrict__ cnt,
    const int* __restrict__ elist, __hip_bfloat16* __restrict__ xcatb,
    const __hip_bfloat16* __restrict__ Wt, float* __restrict__ PaOut,
    __hip_bfloat16* __restrict__ PbbOut) {
    __shared__ __hip_bfloat16 newt[16][72];
    int tid = threadIdx.x;
    int w = tid >> 6, lane = tid & 63;
    int panel = blockIdx.x;
    int r0 = panel * 16;

    // phase A: aggregate 2 nodes per wave
#pragma unroll
    for (int nl = 0; nl < 2; ++nl) {
        int local = w * 2 + nl;
        int node = r0 + local;
        int c = cnt[node];
        if (c > CAP) c = CAP;
        float mx = bucket_max(elist + (size_t)node * CAP, c, lane, PbbIn);
        float v = fmaxf(PaIn[(size_t)node * 64 + lane] + b[lane] + mx, 0.f);
        __hip_bfloat16 h = __float2bfloat16(v);
        newt[local][lane] = h;
        xcatb[(size_t)node * XSTB + (C - 64) + lane] = h;
    }
    __syncthreads();
    if (w >= 2) return;

    // phase B: MFMA gemm for this panel, half = w
    int half = w;
    int m = lane & 15, g = lane >> 4;
    const __hip_bfloat16* aptr = xcatb + (size_t)(r0 + m) * XSTB + g * 8;
    const __hip_bfloat16* bptr = Wt + (size_t)(half * 64 + m) * C + g * 8;
    float4v acc[4] = {{0.f,0.f,0.f,0.f},{0.f,0.f,0.f,0.f},
                      {0.f,0.f,0.f,0.f},{0.f,0.f,0.f,0.f}};
#pragma unroll
    for (int k0 = 0; k0 < C; k0 += 32) {
        short8v a;
        if (k0 < C - 64) a = *(const short8v*)(aptr + k0);
        else             a = *(const short8v*)(&newt[m][k0 - (C - 64) + g * 8]);
#pragma unroll
        for (int t = 0; t < 4; ++t) {
            short8v bb = *(const short8v*)(bptr + (size_t)t * 16 * C + k0);
            acc[t] = __builtin_amdgcn_mfma_f32_16x16x32_bf16(a, bb, acc[t], 0, 0, 0);
        }
    }
    if (half == 0) {
#pragma unroll
        for (int t = 0; t < 4; ++t)
#pragma unroll
            for (int r = 0; r < 4; ++r)
                PaOut[(size_t)(r0 + g * 4 + r) * 64 + t * 16 + m] = acc[t][r];
    } else {
#pragma unroll
        for (int t = 0; t < 4; ++t)
#pragma unroll
            for (int r = 0; r < 4; ++r)
                PbbOut[(size_t)(r0 + g * 4 + r) * 64 + t * 16 + m] =
                    __float2bfloat16(acc[t][r]);
    }
}

// ---- last layer agg + final max (4 nodes/block, 1 per wave) ----
__global__ __launch_bounds__(256, 4) void aggf_kernel(
    const float* __restrict__ Pa, const __hip_bfloat16* __restrict__ Pbb,
    const float* __restrict__ b, const int* __restrict__ cnt,
    const int* __restrict__ elist, const __hip_bfloat16* __restrict__ xcatb,
    float* __restrict__ out) {
    __shared__ float sm[4][64];
    int w = threadIdx.x >> 6, lane = threadIdx.x & 63;
    int node = blockIdx.x * 4 + w;                 // 5000*4 = 20000 exactly
    int c = cnt[node];
    if (c > CAP) c = CAP;
    float mx = bucket_max(elist + (size_t)node * CAP, c, lane, Pbb);
    float v = fmaxf(Pa[(size_t)node * 64 + lane] + b[lane] + mx, 0.f);
    sm[w][lane] = v;                               // intra-wave produce/consume
    float m;
    if (lane < 48) {
        bh4 q = *(const bh4*)(xcatb + (size_t)node * XSTB + (lane << 2));
        float f0 = __bfloat162float(q.a), f1 = __bfloat162float(q.b);
        float f2 = __bfloat162float(q.c), f3 = __bfloat162float(q.d);
        m = fmaxf(fmaxf(f0, f1), fmaxf(f2, f3));
    } else {
        const float* p = &sm[w][(lane - 48) << 2];
        m = fmaxf(fmaxf(p[0], p[1]), fmaxf(p[2], p[3]));
    }
    out[(size_t)node * 64 + lane] = m;
}

extern "C" void kernel_launch(void* const* d_in, const int* in_sizes, int n_in,
                              void* d_out, int out_size, void* d_ws, size_t ws_size,
                              hipStream_t stream) {
    const float* x = (const float*)d_in[0];
    const float* W0 = (const float*)d_in[1];
    const float* W1 = (const float*)d_in[3];
    const float* W2 = (const float*)d_in[5];
    const float* b0 = (const float*)d_in[2];
    const float* b1 = (const float*)d_in[4];
    const float* b2 = (const float*)d_in[6];
    const int* eidx = (const int*)d_in[7];
    const int* esrc = eidx;
    const int* edst = eidx + NE;
    float* out = (float*)d_out;

    char* w = (char*)d_ws;
    __hip_bfloat16* xcatb = (__hip_bfloat16*)w;  w += (size_t)NN * XSTB * 2;
    float* PaA = (float*)w;                      w += (size_t)NN * 64 * 4;
    __hip_bfloat16* PbbA = (__hip_bfloat16*)w;   w += (size_t)NN * 64 * 2;
    float* PaB = (float*)w;                      w += (size_t)NN * 64 * 4;
    __hip_bfloat16* PbbB = (__hip_bfloat16*)w;   w += (size_t)NN * 64 * 2;
    __hip_bfloat16* Wt = (__hip_bfloat16*)w;     w += (size_t)WT_TOT * 2;
    int* cursor = (int*)w;                       w += (size_t)NN * 4;
    int* elist = (int*)w;

    kz_kernel<<<20, 256, 0, stream>>>(cursor);
    k1_kernel<<<3285, 256, 0, stream>>>(x, W0, W1, W2, esrc, edst, xcatb, Wt,
                                        cursor, elist, PaA, PbbA);
    fused_kernel<128><<<1250, 512, 0, stream>>>(PaA, PbbA, b0, cursor, elist, xcatb,
                                                Wt + WT_OFF1, PaB, PbbB);
    fused_kernel<192><<<1250, 512, 0, stream>>>(PaB, PbbB, b1, cursor, elist, xcatb,
                                                Wt + WT_OFF2, PaA, PbbA);
    aggf_kernel<<<5000, 256, 0, stream>>>(PaA, PbbA, b2, cursor, elist, xcatb, out);
}

// Round 13
// 89.055 us; speedup vs baseline: 1.4542x; 1.0505x over previous
//
#include <hip/hip_runtime.h>
#include <hip/hip_bf16.h>

#define NN 20000
#define NE 320000
#define XSTB 256    // xcatb row stride (bf16 elems)
#define CAP 96      // per-node bucket capacity (Poisson(16): P(>=96)~1e-47); CAP%8==0

typedef __attribute__((ext_vector_type(8))) short short8v;
typedef __attribute__((ext_vector_type(4))) float float4v;

struct bh4 { __hip_bfloat16 a, b, c, d; };

// Wt layout (all 3 layers): per layer [128][K] bf16.
// rows 0..63 = (Wtop-Wbot)^T -> Pa; rows 64..127 = Wbot^T -> Pb
#define WT_OFF0 0
#define WT_OFF1 (128 * 64)                 // 8192
#define WT_OFF2 (WT_OFF1 + 128 * 128)      // 24576
#define WT_TOT  (WT_OFF2 + 128 * 192)      // 49152 elems

// ILP-8 bucket max: all 8 gathers issue unconditionally (index clamped to a
// valid slot, select after) -> 8 loads in flight, ~2 serial rounds at deg~16.
__device__ __forceinline__ float bucket_max8(const int* __restrict__ el, int c, int lane,
                                             const __hip_bfloat16* __restrict__ Pbb) {
    float mx = -INFINITY;
    for (int i = 0; i < c; i += 8) {
        int4 ea = *(const int4*)(el + i);
        int4 eb = *(const int4*)(el + i + 4);
        int idx[8] = {ea.x, ea.y, ea.z, ea.w, eb.x, eb.y, eb.z, eb.w};
        float v[8];
#pragma unroll
        for (int j = 0; j < 8; ++j) {
            int id = (i + j < c) ? idx[j] : idx[0];    // idx[0] always valid (i<c)
            float t = __bfloat162float(Pbb[(size_t)id * 64 + lane]);
            v[j] = (i + j < c) ? t : -INFINITY;
        }
        float m0 = fmaxf(fmaxf(v[0], v[1]), fmaxf(v[2], v[3]));
        float m1 = fmaxf(fmaxf(v[4], v[5]), fmaxf(v[6], v[7]));
        mx = fmaxf(mx, fmaxf(m0, m1));
    }
    return mx;
}

// ---- KZ: zero cursor (20 blocks) || build Wt all layers (192 blocks) ----
__global__ __launch_bounds__(256) void kz_kernel(const float* __restrict__ W0,
                                                 const float* __restrict__ W1,
                                                 const float* __restrict__ W2,
                                                 __hip_bfloat16* __restrict__ Wt,
                                                 int* __restrict__ cursor) {
    int blk = blockIdx.x, tid = threadIdx.x;
    if (blk < 20) {
        int q = blk * 256 + tid;               // 5120 >= 5000 int4
        if (q < NN / 4) *((int4*)cursor + q) = make_int4(0, 0, 0, 0);
    } else {
        int e = (blk - 20) * 256 + tid;        // 49152 exactly
        const float* W;
        int K, off;
        if (e < WT_OFF1) { W = W0; K = 64;  off = WT_OFF0; }
        else if (e < WT_OFF2) { W = W1; K = 128; off = WT_OFF1; }
        else { W = W2; K = 192; off = WT_OFF2; }
        int el = e - off;
        int j = el / K, k = el - j * K;
        float wv;
        if (j < 64) wv = W[(size_t)k * 64 + j] - W[(size_t)(K + k) * 64 + j];
        else        wv = W[(size_t)(K + k) * 64 + (j - 64)];
        Wt[(size_t)off + (size_t)j * K + k] = __float2bfloat16(wv);
    }
}

// ---- K1: (gemm0 + xconv) || bucket CSR fill ----
// blocks [0,625): gemm0 for 2 panels (A from fp32 x, B from global Wt0) AND
//                 convert the same 32 x-rows to bf16 xcatb[:,0:64].
// blocks [625,1875): bucket fill.
__global__ __launch_bounds__(256, 4) void k1_kernel(
    const float* __restrict__ x, const __hip_bfloat16* __restrict__ Wt,
    const int* __restrict__ esrc, const int* __restrict__ edst,
    __hip_bfloat16* __restrict__ xcatb, int* __restrict__ cursor,
    int* __restrict__ elist, float* __restrict__ Pa,
    __hip_bfloat16* __restrict__ Pbb) {
    int blk = blockIdx.x, tid = threadIdx.x;
    int w = tid >> 6, lane = tid & 63;

    if (blk < 625) {
        // xconv: wave w converts rows blk*32 + w*8 + (lane>>3), cols (lane&7)*8..+7
        {
            int row = blk * 32 + w * 8 + (lane >> 3);
            int c8 = (lane & 7) << 3;
            float4 a0 = *(const float4*)(x + (size_t)row * 64 + c8);
            float4 a1 = *(const float4*)(x + (size_t)row * 64 + c8 + 4);
            bh4 o0 = {__float2bfloat16(a0.x), __float2bfloat16(a0.y),
                      __float2bfloat16(a0.z), __float2bfloat16(a0.w)};
            bh4 o1 = {__float2bfloat16(a1.x), __float2bfloat16(a1.y),
                      __float2bfloat16(a1.z), __float2bfloat16(a1.w)};
            *(bh4*)(xcatb + (size_t)row * XSTB + c8) = o0;
            *(bh4*)(xcatb + (size_t)row * XSTB + c8 + 4) = o1;
        }
        // gemm0
        int wid = blk * 4 + w;                     // 0..2499
        int panel = wid >> 1, half = wid & 1;
        int m = lane & 15, g = lane >> 4;
        const float* aptr = x + (size_t)(panel * 16 + m) * 64 + g * 8;
        const __hip_bfloat16* bptr = Wt + (size_t)(half * 64 + m) * 64 + g * 8;
        float4v acc[4] = {{0.f,0.f,0.f,0.f},{0.f,0.f,0.f,0.f},
                          {0.f,0.f,0.f,0.f},{0.f,0.f,0.f,0.f}};
#pragma unroll
        for (int k0 = 0; k0 < 64; k0 += 32) {
            float4 a0 = *(const float4*)(aptr + k0);
            float4 a1 = *(const float4*)(aptr + k0 + 4);
            __hip_bfloat16 ah[8] = {
                __float2bfloat16(a0.x), __float2bfloat16(a0.y),
                __float2bfloat16(a0.z), __float2bfloat16(a0.w),
                __float2bfloat16(a1.x), __float2bfloat16(a1.y),
                __float2bfloat16(a1.z), __float2bfloat16(a1.w)};
            short8v a = *(const short8v*)ah;
#pragma unroll
            for (int t = 0; t < 4; ++t) {
                short8v bb = *(const short8v*)(bptr + (size_t)t * 16 * 64 + k0);
                acc[t] = __builtin_amdgcn_mfma_f32_16x16x32_bf16(a, bb, acc[t], 0, 0, 0);
            }
        }
        int r0 = panel * 16;
        if (half == 0) {
#pragma unroll
            for (int t = 0; t < 4; ++t)
#pragma unroll
                for (int r = 0; r < 4; ++r)
                    Pa[(size_t)(r0 + g * 4 + r) * 64 + t * 16 + m] = acc[t][r];
        } else {
#pragma unroll
            for (int t = 0; t < 4; ++t)
#pragma unroll
                for (int r = 0; r < 4; ++r)
                    Pbb[(size_t)(r0 + g * 4 + r) * 64 + t * 16 + m] =
                        __float2bfloat16(acc[t][r]);
        }
    } else {
        int i = (blk - 625) * 256 + tid;           // < NE exactly
        int d = edst[i];
        int pos = atomicAdd(cursor + d, 1);
        if (pos < CAP) elist[(size_t)d * CAP + pos] = esrc[i];
    }
}

// ---- fused: agg(layer i) for 16 nodes -> LDS + xcatb, then gemm(layer i+1) K=C ----
// 1250 blocks x 256 threads. Phase A: 4 waves x 4 nodes, ILP-8 gather.
// Phase B: waves 0,1 (halves).
template <int C>
__global__ __launch_bounds__(256, 4) void fused_kernel(
    const float* __restrict__ PaIn, const __hip_bfloat16* __restrict__ PbbIn,
    const float* __restrict__ b, const int* __restrict__ cnt,
    const int* __restrict__ elist, __hip_bfloat16* __restrict__ xcatb,
    const __hip_bfloat16* __restrict__ Wt, float* __restrict__ PaOut,
    __hip_bfloat16* __restrict__ PbbOut) {
    __shared__ __hip_bfloat16 newt[16][72];
    int tid = threadIdx.x;
    int w = tid >> 6, lane = tid & 63;
    int panel = blockIdx.x;
    int r0 = panel * 16;

    // phase A: aggregate 4 nodes per wave, ILP-8 per node
#pragma unroll
    for (int nl = 0; nl < 4; ++nl) {
        int local = w * 4 + nl;
        int node = r0 + local;
        int c = cnt[node];
        if (c > CAP) c = CAP;
        float mx = bucket_max8(elist + (size_t)node * CAP, c, lane, PbbIn);
        float v = fmaxf(PaIn[(size_t)node * 64 + lane] + b[lane] + mx, 0.f);
        __hip_bfloat16 h = __float2bfloat16(v);
        newt[local][lane] = h;
        xcatb[(size_t)node * XSTB + (C - 64) + lane] = h;
    }
    __syncthreads();
    if (w >= 2) return;

    // phase B: MFMA gemm for this panel, half = w
    int half = w;
    int m = lane & 15, g = lane >> 4;
    const __hip_bfloat16* aptr = xcatb + (size_t)(r0 + m) * XSTB + g * 8;
    const __hip_bfloat16* bptr = Wt + (size_t)(half * 64 + m) * C + g * 8;
    float4v acc[4] = {{0.f,0.f,0.f,0.f},{0.f,0.f,0.f,0.f},
                      {0.f,0.f,0.f,0.f},{0.f,0.f,0.f,0.f}};
#pragma unroll
    for (int k0 = 0; k0 < C; k0 += 32) {
        short8v a;
        if (k0 < C - 64) a = *(const short8v*)(aptr + k0);
        else             a = *(const short8v*)(&newt[m][k0 - (C - 64) + g * 8]);
#pragma unroll
        for (int t = 0; t < 4; ++t) {
            short8v bb = *(const short8v*)(bptr + (size_t)t * 16 * C + k0);
            acc[t] = __builtin_amdgcn_mfma_f32_16x16x32_bf16(a, bb, acc[t], 0, 0, 0);
        }
    }
    if (half == 0) {
#pragma unroll
        for (int t = 0; t < 4; ++t)
#pragma unroll
            for (int r = 0; r < 4; ++r)
                PaOut[(size_t)(r0 + g * 4 + r) * 64 + t * 16 + m] = acc[t][r];
    } else {
#pragma unroll
        for (int t = 0; t < 4; ++t)
#pragma unroll
            for (int r = 0; r < 4; ++r)
                PbbOut[(size_t)(r0 + g * 4 + r) * 64 + t * 16 + m] =
                    __float2bfloat16(acc[t][r]);
    }
}

// ---- last layer agg + final max (4 nodes/block, 1 per wave, ILP-8) ----
__global__ __launch_bounds__(256, 4) void aggf_kernel(
    const float* __restrict__ Pa, const __hip_bfloat16* __restrict__ Pbb,
    const float* __restrict__ b, const int* __restrict__ cnt,
    const int* __restrict__ elist, const __hip_bfloat16* __restrict__ xcatb,
    float* __restrict__ out) {
    __shared__ float sm[4][64];
    int w = threadIdx.x >> 6, lane = threadIdx.x & 63;
    int node = blockIdx.x * 4 + w;                 // 5000*4 = 20000 exactly
    int c = cnt[node];
    if (c > CAP) c = CAP;
    float mx = bucket_max8(elist + (size_t)node * CAP, c, lane, Pbb);
    float v = fmaxf(Pa[(size_t)node * 64 + lane] + b[lane] + mx, 0.f);
    sm[w][lane] = v;                               // intra-wave produce/consume
    float m;
    if (lane < 48) {
        bh4 q = *(const bh4*)(xcatb + (size_t)node * XSTB + (lane << 2));
        float f0 = __bfloat162float(q.a), f1 = __bfloat162float(q.b);
        float f2 = __bfloat162float(q.c), f3 = __bfloat162float(q.d);
        m = fmaxf(fmaxf(f0, f1), fmaxf(f2, f3));
    } else {
        const float* p = &sm[w][(lane - 48) << 2];
        m = fmaxf(fmaxf(p[0], p[1]), fmaxf(p[2], p[3]));
    }
    out[(size_t)node * 64 + lane] = m;
}

extern "C" void kernel_launch(void* const* d_in, const int* in_sizes, int n_in,
                              void* d_out, int out_size, void* d_ws, size_t ws_size,
                              hipStream_t stream) {
    const float* x = (const float*)d_in[0];
    const float* W0 = (const float*)d_in[1];
    const float* W1 = (const float*)d_in[3];
    const float* W2 = (const float*)d_in[5];
    const float* b0 = (const float*)d_in[2];
    const float* b1 = (const float*)d_in[4];
    const float* b2 = (const float*)d_in[6];
    const int* eidx = (const int*)d_in[7];
    const int* esrc = eidx;
    const int* edst = eidx + NE;
    float* out = (float*)d_out;

    char* w = (char*)d_ws;
    __hip_bfloat16* xcatb = (__hip_bfloat16*)w;  w += (size_t)NN * XSTB * 2;
    float* PaA = (float*)w;                      w += (size_t)NN * 64 * 4;
    __hip_bfloat16* PbbA = (__hip_bfloat16*)w;   w += (size_t)NN * 64 * 2;
    float* PaB = (float*)w;                      w += (size_t)NN * 64 * 4;
    __hip_bfloat16* PbbB = (__hip_bfloat16*)w;   w += (size_t)NN * 64 * 2;
    __hip_bfloat16* Wt = (__hip_bfloat16*)w;     w += (size_t)WT_TOT * 2;
    int* cursor = (int*)w;                       w += (size_t)NN * 4;
    int* elist = (int*)w;

    kz_kernel<<<20 + 192, 256, 0, stream>>>(W0, W1, W2, Wt, cursor);
    k1_kernel<<<1875, 256, 0, stream>>>(x, Wt, esrc, edst, xcatb, cursor, elist,
                                        PaA, PbbA);
    fused_kernel<128><<<1250, 256, 0, stream>>>(PaA, PbbA, b0, cursor, elist, xcatb,
                                                Wt + WT_OFF1, PaB, PbbB);
    fused_kernel<192><<<1250, 256, 0, stream>>>(PbbB == nullptr ? PaA : PaB, PbbB, b1,
                                                cursor, elist, xcatb,
                                                Wt + WT_OFF2, PaA, PbbA);
    aggf_kernel<<<5000, 256, 0, stream>>>(PaA, PbbA, b2, cursor, elist, xcatb, out);
}